// Round 3
// baseline (209.667 us; speedup 1.0000x reference)
//
#include <hip/hip_runtime.h>
#include <hip/hip_bf16.h>

// Chamfer distance: B=8, N=M=4096, D=128, fp32 inputs, scalar fp32 out.
// dist[b,n,m] = ||p1||^2 + ||p2||^2 - 2*p1.p2
// bf1 holds (-2*p1) in bf16, so MFMA acc = -2*cross directly.
// out = mean_n(min_m dist) + mean_m(min_n dist)

#define BATCH 8
#define NPTS 4096
#define DIM 128

using bf16x8 = __attribute__((ext_vector_type(8))) short;
using f32x4  = __attribute__((ext_vector_type(4))) float;

// ------------- K1: fp32 -> bf16 (p1 scaled by -2) + exact fp32 norms --------
__global__ void prep_kernel(const float* __restrict__ p1,
                            const float* __restrict__ p2,
                            __hip_bfloat16* __restrict__ b1,
                            __hip_bfloat16* __restrict__ b2,
                            float* __restrict__ s1,
                            float* __restrict__ s2) {
    const int arr = blockIdx.y;
    const float* src = arr ? p2 : p1;
    __hip_bfloat16* dst = arr ? b2 : b1;
    float* sq = arr ? s2 : s1;
    const float scale = arr ? 1.0f : -2.0f;

    const int wid = threadIdx.x >> 6;
    const int l   = threadIdx.x & 63;
    const int p   = blockIdx.x * 4 + wid;   // one wave per point
    const float2 v = *reinterpret_cast<const float2*>(src + (size_t)p * DIM + l * 2);
    float s = v.x * v.x + v.y * v.y;        // norm from ORIGINAL values
    __hip_bfloat162 h = __float22bfloat162_rn(make_float2(v.x * scale, v.y * scale));
    *reinterpret_cast<__hip_bfloat162*>(dst + (size_t)p * DIM + l * 2) = h;
    #pragma unroll
    for (int off = 1; off < 64; off <<= 1) s += __shfl_xor(s, off);
    if (l == 0) sq[p] = s;
}

// ------------- K2: tiled GEMM + fused directional mins ----------------------
// grid (32 n-tiles, 4 m-quarters, 8 batches) = 1024 blocks, 256 threads.
// Block: 128 rows x 1024 cols (8 m-tiles of 128). Wave: 32 rows.
__global__ void __launch_bounds__(256, 4)
chamfer_tile_kernel(const __hip_bfloat16* __restrict__ bf1,
                    const __hip_bfloat16* __restrict__ bf2,
                    const float* __restrict__ sq1,
                    const float* __restrict__ sq2,
                    float* __restrict__ min1p,   // [B][4][NPTS]  (sq2 - 2c) row-mins
                    float* __restrict__ min2p) { // [B][128][NPTS] (sq1 - 2c) col-mins
    const int nt = blockIdx.x;
    const int mh = blockIdx.y;      // m quarter (1024 cols)
    const int b  = blockIdx.z;
    const int tid = threadIdx.x;
    const int wid = tid >> 6;
    const int l   = tid & 63;
    const int l15 = l & 15;
    const int lhi = l >> 4;

    __shared__ __align__(16) unsigned char btile[128 * 256]; // 128 rows x 256B
    __shared__ float sq2b[128];

    const __hip_bfloat16* bf1b = bf1 + (size_t)b * NPTS * DIM;
    const __hip_bfloat16* bf2b = bf2 + (size_t)b * NPTS * DIM;

    const int n0 = nt * 128 + wid * 32;  // wave's first row

    // A fragments: rows n0 + rt*16 + l15, k = ks*32 + lhi*8
    bf16x8 afrag[2][4];
    #pragma unroll
    for (int rt = 0; rt < 2; ++rt)
        #pragma unroll
        for (int ks = 0; ks < 4; ++ks)
            afrag[rt][ks] = *reinterpret_cast<const bf16x8*>(
                bf1b + (n0 + rt * 16 + l15) * DIM + ks * 32 + lhi * 8);

    // sq1 for accumulator rows: n0 + rt*16 + lhi*4 + j
    float sq1v[2][4];
    #pragma unroll
    for (int rt = 0; rt < 2; ++rt)
        #pragma unroll
        for (int j = 0; j < 4; ++j)
            sq1v[rt][j] = sq1[b * NPTS + n0 + rt * 16 + lhi * 4 + j];

    float rmin[2][4];
    #pragma unroll
    for (int rt = 0; rt < 2; ++rt)
        #pragma unroll
        for (int j = 0; j < 4; ++j) rmin[rt][j] = 3.4e38f;

    for (int mt = 0; mt < 8; ++mt) {
        const int m0 = mh * 1024 + mt * 128;

        __syncthreads(); // btile readers from previous iteration done

        // stage B tile with XOR swizzle; 8 x 16B per thread
        #pragma unroll
        for (int i = 0; i < 8; ++i) {
            const int c = i * 256 + tid;
            const int row = c >> 4;
            const int q   = c & 15;
            bf16x8 v = *reinterpret_cast<const bf16x8*>(
                bf2b + (m0 + row) * DIM + q * 8);
            const int dst = row * 256 + ((q * 16) ^ ((row & 7) << 4));
            *reinterpret_cast<bf16x8*>(&btile[dst]) = v;
        }
        if (tid < 128) sq2b[tid] = sq2[b * NPTS + m0 + tid];
        __syncthreads();

        // MFMA: acc = (-2*P1rows) x P2rows^T, K=128
        f32x4 acc[2][8];
        #pragma unroll
        for (int rt = 0; rt < 2; ++rt)
            #pragma unroll
            for (int ct = 0; ct < 8; ++ct) acc[rt][ct] = f32x4{0.f, 0.f, 0.f, 0.f};

        #pragma unroll
        for (int ks = 0; ks < 4; ++ks) {
            #pragma unroll
            for (int ct = 0; ct < 8; ++ct) {
                const int brow = ct * 16 + l15;
                const int kbyte = ks * 64 + lhi * 16;
                bf16x8 bfrag = *reinterpret_cast<const bf16x8*>(
                    &btile[brow * 256 + (kbyte ^ ((brow & 7) << 4))]);
                #pragma unroll
                for (int rt = 0; rt < 2; ++rt)
                    acc[rt][ct] = __builtin_amdgcn_mfma_f32_16x16x32_bf16(
                        afrag[rt][ks], bfrag, acc[rt][ct], 0, 0, 0);
            }
        }

        // per-lane sq2 values for each col group
        float s2v[8];
        #pragma unroll
        for (int ct = 0; ct < 8; ++ct) s2v[ct] = sq2b[ct * 16 + l15];

        // dir1: row-mins (min over cols), min3-friendly pairs over ct
        #pragma unroll
        for (int rt = 0; rt < 2; ++rt)
            #pragma unroll
            for (int j = 0; j < 4; ++j) {
                float r = rmin[rt][j];
                #pragma unroll
                for (int cp = 0; cp < 4; ++cp) {
                    const float t0 = acc[rt][2 * cp][j]     + s2v[2 * cp];
                    const float t1 = acc[rt][2 * cp + 1][j] + s2v[2 * cp + 1];
                    r = fminf(r, fminf(t0, t1));   // v_min3
                }
                rmin[rt][j] = r;
            }

        // dir2: col-mins (min over this wave's 32 rows), pairs over j
        float cmin[8];
        #pragma unroll
        for (int ct = 0; ct < 8; ++ct) {
            float c = 3.4e38f;
            #pragma unroll
            for (int rt = 0; rt < 2; ++rt)
                #pragma unroll
                for (int jp = 0; jp < 2; ++jp) {
                    const float u0 = sq1v[rt][2 * jp]     + acc[rt][ct][2 * jp];
                    const float u1 = sq1v[rt][2 * jp + 1] + acc[rt][ct][2 * jp + 1];
                    c = fminf(c, fminf(u0, u1));   // v_min3
                }
            cmin[ct] = c;
        }

        // fold the 4 lhi row-groups, then write per-wave partial to global
        #pragma unroll
        for (int ct = 0; ct < 8; ++ct) {
            cmin[ct] = fminf(cmin[ct], __shfl_xor(cmin[ct], 16));
            cmin[ct] = fminf(cmin[ct], __shfl_xor(cmin[ct], 32));
        }
        if (l < 16) {
            float* dst = min2p + ((size_t)b * 128 + nt * 4 + wid) * NPTS + m0;
            #pragma unroll
            for (int ct = 0; ct < 8; ++ct) dst[ct * 16 + l] = cmin[ct];
        }
    }

    // dir1 finalize: reduce across lane bits 0..3 (cols), write once per row
    #pragma unroll
    for (int rt = 0; rt < 2; ++rt)
        #pragma unroll
        for (int j = 0; j < 4; ++j) {
            float v = rmin[rt][j];
            v = fminf(v, __shfl_xor(v, 1));
            v = fminf(v, __shfl_xor(v, 2));
            v = fminf(v, __shfl_xor(v, 4));
            v = fminf(v, __shfl_xor(v, 8));
            rmin[rt][j] = v;
        }
    if (l15 == 0) {
        #pragma unroll
        for (int rt = 0; rt < 2; ++rt)
            #pragma unroll
            for (int j = 0; j < 4; ++j)
                min1p[((size_t)b * 4 + mh) * NPTS + n0 + rt * 16 + lhi * 4 + j] =
                    rmin[rt][j];
    }
}

// ------------- K3: combine partials, means, scalar out ----------------------
__global__ void finalize_kernel(const float* __restrict__ min1p,
                                const float* __restrict__ min2p,
                                const float* __restrict__ sq1,
                                const float* __restrict__ sq2,
                                float* __restrict__ out) {
    const int tid = threadIdx.x;
    const int gid = blockIdx.x * 256 + tid;   // 512 blocks -> 131072 threads
    float sum = 0.f;

    if (gid < BATCH * NPTS) {
        // dir1: one (b,n) per thread
        const int b = gid >> 12, n = gid & (NPTS - 1);
        const float* p = min1p + (size_t)b * 4 * NPTS + n;
        float v = fminf(fminf(p[0], p[NPTS]), fminf(p[2 * NPTS], p[3 * NPTS]));
        sum = (v + sq1[gid]) * (1.0f / (BATCH * NPTS));
    } else if (gid < 2 * BATCH * NPTS) {
        // dir2: one (b,m) per thread, reduce 128 partials
        const int idx = gid - BATCH * NPTS;
        const int b = idx >> 12, m = idx & (NPTS - 1);
        const float* p = min2p + (size_t)b * 128 * NPTS + m;
        float v0 = 3.4e38f, v1 = 3.4e38f;
        #pragma unroll 4
        for (int j = 0; j < 128; j += 2) {
            v0 = fminf(v0, p[(size_t)j * NPTS]);
            v1 = fminf(v1, p[(size_t)(j + 1) * NPTS]);
        }
        sum = (fminf(v0, v1) + sq2[idx]) * (1.0f / (BATCH * NPTS));
    }

    #pragma unroll
    for (int off = 1; off < 64; off <<= 1) sum += __shfl_xor(sum, off);
    __shared__ float wsum[4];
    if ((tid & 63) == 0) wsum[tid >> 6] = sum;
    __syncthreads();
    if (tid == 0) atomicAdd(out, wsum[0] + wsum[1] + wsum[2] + wsum[3]);
}

extern "C" void kernel_launch(void* const* d_in, const int* in_sizes, int n_in,
                              void* d_out, int out_size, void* d_ws, size_t ws_size,
                              hipStream_t stream) {
    const float* p1 = (const float*)d_in[0];
    const float* p2 = (const float*)d_in[1];
    float* out = (float*)d_out;

    const size_t npts_tot = (size_t)BATCH * NPTS;
    __hip_bfloat16* bf1 = (__hip_bfloat16*)d_ws;
    __hip_bfloat16* bf2 = bf1 + npts_tot * DIM;
    float* sq1   = (float*)(bf2 + npts_tot * DIM);
    float* sq2   = sq1 + npts_tot;
    float* min1p = sq2 + npts_tot;                         // [B][4][NPTS]
    float* min2p = min1p + (size_t)BATCH * 4 * NPTS;       // [B][128][NPTS]

    hipMemsetAsync(d_out, 0, sizeof(float), stream);

    prep_kernel<<<dim3(npts_tot / 4, 2), 256, 0, stream>>>(p1, p2, bf1, bf2, sq1, sq2);

    dim3 g2(32, 4, BATCH);
    chamfer_tile_kernel<<<g2, 256, 0, stream>>>(bf1, bf2, sq1, sq2, min1p, min2p);

    finalize_kernel<<<512, 256, 0, stream>>>(min1p, min2p, sq1, sq2, out);
}

// Round 4
// 146.670 us; speedup vs baseline: 1.4295x; 1.4295x over previous
//
#include <hip/hip_runtime.h>
#include <hip/hip_bf16.h>

// Chamfer distance: B=8, N=M=4096, D=128, fp32 inputs, scalar fp32 out.
// dist[b,n,m] = ||p1||^2 + ||p2||^2 - 2*p1.p2
// bf1 holds (-2*p1) in bf16, so MFMA acc = -2*cross directly.
// out = mean_n(min_m dist) + mean_m(min_n dist)

#define BATCH 8
#define NPTS 4096
#define DIM 128

using bf16x8 = __attribute__((ext_vector_type(8))) short;
using f32x4  = __attribute__((ext_vector_type(4))) float;

// ------------- K1: fp32 -> bf16 (p1 scaled by -2) + exact fp32 norms --------
__global__ void prep_kernel(const float* __restrict__ p1,
                            const float* __restrict__ p2,
                            __hip_bfloat16* __restrict__ b1,
                            __hip_bfloat16* __restrict__ b2,
                            float* __restrict__ s1,
                            float* __restrict__ s2) {
    const int arr = blockIdx.y;
    const float* src = arr ? p2 : p1;
    __hip_bfloat16* dst = arr ? b2 : b1;
    float* sq = arr ? s2 : s1;
    const float scale = arr ? 1.0f : -2.0f;

    const int wid = threadIdx.x >> 6;
    const int l   = threadIdx.x & 63;
    const int p   = blockIdx.x * 4 + wid;   // one wave per point
    const float2 v = *reinterpret_cast<const float2*>(src + (size_t)p * DIM + l * 2);
    float s = v.x * v.x + v.y * v.y;        // norm from ORIGINAL values
    __hip_bfloat162 h = __float22bfloat162_rn(make_float2(v.x * scale, v.y * scale));
    *reinterpret_cast<__hip_bfloat162*>(dst + (size_t)p * DIM + l * 2) = h;
    #pragma unroll
    for (int off = 1; off < 64; off <<= 1) s += __shfl_xor(s, off);
    if (l == 0) sq[p] = s;
}

// ------------- K2: tiled GEMM + fused directional mins ----------------------
// grid (32 n-tiles, 4 m-quarters, 8 batches) = 1024 blocks, 256 threads.
// Block: 128 rows x 1024 cols (8 m-tiles of 128). Wave: 32 rows.
// launch_bounds (256,2): cap 256 VGPR; compiler lands ~116 which naturally
// allows 4 waves/SIMD (<=128). Forcing (256,4) made the allocator cut to 64
// VGPR -> scratch spills (R2: FETCH 37->239MB, K2 63->128us). Do NOT force.
__global__ void __launch_bounds__(256, 2)
chamfer_tile_kernel(const __hip_bfloat16* __restrict__ bf1,
                    const __hip_bfloat16* __restrict__ bf2,
                    const float* __restrict__ sq1,
                    const float* __restrict__ sq2,
                    float* __restrict__ min1p,   // [B][4][NPTS]  (sq2 - 2c) row-mins
                    float* __restrict__ min2p) { // [B][128][NPTS] (sq1 - 2c) col-mins
    const int nt = blockIdx.x;
    const int mh = blockIdx.y;      // m quarter (1024 cols)
    const int b  = blockIdx.z;
    const int tid = threadIdx.x;
    const int wid = tid >> 6;
    const int l   = tid & 63;
    const int l15 = l & 15;
    const int lhi = l >> 4;

    __shared__ __align__(16) unsigned char btile[128 * 256]; // 128 rows x 256B

    const __hip_bfloat16* bf1b = bf1 + (size_t)b * NPTS * DIM;
    const __hip_bfloat16* bf2b = bf2 + (size_t)b * NPTS * DIM;
    const float* sq2b = sq2 + b * NPTS;

    const int n0 = nt * 128 + wid * 32;  // wave's first row

    // A fragments: rows n0 + rt*16 + l15, k = ks*32 + lhi*8
    bf16x8 afrag[2][4];
    #pragma unroll
    for (int rt = 0; rt < 2; ++rt)
        #pragma unroll
        for (int ks = 0; ks < 4; ++ks)
            afrag[rt][ks] = *reinterpret_cast<const bf16x8*>(
                bf1b + (n0 + rt * 16 + l15) * DIM + ks * 32 + lhi * 8);

    // sq1 for accumulator rows: n0 + rt*16 + lhi*4 + j
    float sq1v[2][4];
    #pragma unroll
    for (int rt = 0; rt < 2; ++rt)
        #pragma unroll
        for (int j = 0; j < 4; ++j)
            sq1v[rt][j] = sq1[b * NPTS + n0 + rt * 16 + lhi * 4 + j];

    float rmin[2][4];
    #pragma unroll
    for (int rt = 0; rt < 2; ++rt)
        #pragma unroll
        for (int j = 0; j < 4; ++j) rmin[rt][j] = 3.4e38f;

    for (int mt = 0; mt < 8; ++mt) {
        const int m0 = mh * 1024 + mt * 128;

        __syncthreads(); // btile readers from previous iteration done

        // stage B tile with XOR swizzle; 8 x 16B per thread
        #pragma unroll
        for (int i = 0; i < 8; ++i) {
            const int c = i * 256 + tid;
            const int row = c >> 4;
            const int q   = c & 15;
            bf16x8 v = *reinterpret_cast<const bf16x8*>(
                bf2b + (m0 + row) * DIM + q * 8);
            const int dst = row * 256 + ((q * 16) ^ ((row & 7) << 4));
            *reinterpret_cast<bf16x8*>(&btile[dst]) = v;
        }
        __syncthreads();

        // MFMA: acc = (-2*P1rows) x P2rows^T, K=128
        f32x4 acc[2][8];
        #pragma unroll
        for (int rt = 0; rt < 2; ++rt)
            #pragma unroll
            for (int ct = 0; ct < 8; ++ct) acc[rt][ct] = f32x4{0.f, 0.f, 0.f, 0.f};

        #pragma unroll
        for (int ks = 0; ks < 4; ++ks) {
            #pragma unroll
            for (int ct = 0; ct < 8; ++ct) {
                const int brow = ct * 16 + l15;
                const int kbyte = ks * 64 + lhi * 16;
                bf16x8 bfrag = *reinterpret_cast<const bf16x8*>(
                    &btile[brow * 256 + (kbyte ^ ((brow & 7) << 4))]);
                #pragma unroll
                for (int rt = 0; rt < 2; ++rt)
                    acc[rt][ct] = __builtin_amdgcn_mfma_f32_16x16x32_bf16(
                        afrag[rt][ks], bfrag, acc[rt][ct], 0, 0, 0);
            }
        }

        // per-lane sq2 values for each col group (L1-resident, 512B/tile)
        float s2v[8];
        #pragma unroll
        for (int ct = 0; ct < 8; ++ct) s2v[ct] = sq2b[m0 + ct * 16 + l15];

        // dir1: row-mins (min over cols), min3-friendly pairs over ct
        #pragma unroll
        for (int rt = 0; rt < 2; ++rt)
            #pragma unroll
            for (int j = 0; j < 4; ++j) {
                float r = rmin[rt][j];
                #pragma unroll
                for (int cp = 0; cp < 4; ++cp) {
                    const float t0 = acc[rt][2 * cp][j]     + s2v[2 * cp];
                    const float t1 = acc[rt][2 * cp + 1][j] + s2v[2 * cp + 1];
                    r = fminf(r, fminf(t0, t1));   // v_min3
                }
                rmin[rt][j] = r;
            }

        // dir2: col-mins (min over this wave's 32 rows), pairs over j
        float cmin[8];
        #pragma unroll
        for (int ct = 0; ct < 8; ++ct) {
            float c = 3.4e38f;
            #pragma unroll
            for (int rt = 0; rt < 2; ++rt)
                #pragma unroll
                for (int jp = 0; jp < 2; ++jp) {
                    const float u0 = sq1v[rt][2 * jp]     + acc[rt][ct][2 * jp];
                    const float u1 = sq1v[rt][2 * jp + 1] + acc[rt][ct][2 * jp + 1];
                    c = fminf(c, fminf(u0, u1));   // v_min3
                }
            cmin[ct] = c;
        }

        // fold the 4 lhi row-groups, then write per-wave partial to global
        #pragma unroll
        for (int ct = 0; ct < 8; ++ct) {
            cmin[ct] = fminf(cmin[ct], __shfl_xor(cmin[ct], 16));
            cmin[ct] = fminf(cmin[ct], __shfl_xor(cmin[ct], 32));
        }
        if (l < 16) {
            float* dst = min2p + ((size_t)b * 128 + nt * 4 + wid) * NPTS + m0;
            #pragma unroll
            for (int ct = 0; ct < 8; ++ct) dst[ct * 16 + l] = cmin[ct];
        }
    }

    // dir1 finalize: reduce across lane bits 0..3 (cols), write once per row
    #pragma unroll
    for (int rt = 0; rt < 2; ++rt)
        #pragma unroll
        for (int j = 0; j < 4; ++j) {
            float v = rmin[rt][j];
            v = fminf(v, __shfl_xor(v, 1));
            v = fminf(v, __shfl_xor(v, 2));
            v = fminf(v, __shfl_xor(v, 4));
            v = fminf(v, __shfl_xor(v, 8));
            rmin[rt][j] = v;
        }
    if (l15 == 0) {
        #pragma unroll
        for (int rt = 0; rt < 2; ++rt)
            #pragma unroll
            for (int j = 0; j < 4; ++j)
                min1p[((size_t)b * 4 + mh) * NPTS + n0 + rt * 16 + lhi * 4 + j] =
                    rmin[rt][j];
    }
}

// ------------- K3: combine partials, means, scalar out ----------------------
// 256 blocks x 256 threads = 65536 = 2 * B * NPTS (exact, no guards)
__global__ void finalize_kernel(const float* __restrict__ min1p,
                                const float* __restrict__ min2p,
                                const float* __restrict__ sq1,
                                const float* __restrict__ sq2,
                                float* __restrict__ out) {
    const int tid = threadIdx.x;
    const int gid = blockIdx.x * 256 + tid;
    float sum;

    if (gid < BATCH * NPTS) {
        // dir1: one (b,n) per thread
        const int b = gid >> 12, n = gid & (NPTS - 1);
        const float* p = min1p + (size_t)b * 4 * NPTS + n;
        float v = fminf(fminf(p[0], p[NPTS]), fminf(p[2 * NPTS], p[3 * NPTS]));
        sum = (v + sq1[gid]) * (1.0f / (BATCH * NPTS));
    } else {
        // dir2: one (b,m) per thread, reduce 128 partials (coalesced per j)
        const int idx = gid - BATCH * NPTS;
        const int b = idx >> 12, m = idx & (NPTS - 1);
        const float* p = min2p + (size_t)b * 128 * NPTS + m;
        float v0 = 3.4e38f, v1 = 3.4e38f;
        #pragma unroll 4
        for (int j = 0; j < 128; j += 2) {
            v0 = fminf(v0, p[(size_t)j * NPTS]);
            v1 = fminf(v1, p[(size_t)(j + 1) * NPTS]);
        }
        sum = (fminf(v0, v1) + sq2[idx]) * (1.0f / (BATCH * NPTS));
    }

    #pragma unroll
    for (int off = 1; off < 64; off <<= 1) sum += __shfl_xor(sum, off);
    __shared__ float wsum[4];
    if ((tid & 63) == 0) wsum[tid >> 6] = sum;
    __syncthreads();
    if (tid == 0) atomicAdd(out, wsum[0] + wsum[1] + wsum[2] + wsum[3]);
}

extern "C" void kernel_launch(void* const* d_in, const int* in_sizes, int n_in,
                              void* d_out, int out_size, void* d_ws, size_t ws_size,
                              hipStream_t stream) {
    const float* p1 = (const float*)d_in[0];
    const float* p2 = (const float*)d_in[1];
    float* out = (float*)d_out;

    const size_t npts_tot = (size_t)BATCH * NPTS;
    __hip_bfloat16* bf1 = (__hip_bfloat16*)d_ws;
    __hip_bfloat16* bf2 = bf1 + npts_tot * DIM;
    float* sq1   = (float*)(bf2 + npts_tot * DIM);
    float* sq2   = sq1 + npts_tot;
    float* min1p = sq2 + npts_tot;                         // [B][4][NPTS]
    float* min2p = min1p + (size_t)BATCH * 4 * NPTS;       // [B][128][NPTS]

    hipMemsetAsync(d_out, 0, sizeof(float), stream);

    prep_kernel<<<dim3(npts_tot / 4, 2), 256, 0, stream>>>(p1, p2, bf1, bf2, sq1, sq2);

    dim3 g2(32, 4, BATCH);
    chamfer_tile_kernel<<<g2, 256, 0, stream>>>(bf1, bf2, sq1, sq2, min1p, min2p);

    finalize_kernel<<<256, 256, 0, stream>>>(min1p, min2p, sq1, sq2, out);
}

// Round 5
// 139.625 us; speedup vs baseline: 1.5016x; 1.0505x over previous
//
#include <hip/hip_runtime.h>
#include <hip/hip_bf16.h>

// Chamfer distance: B=8, N=M=4096, D=128, fp32 inputs, scalar fp32 out.
// dist[b,n,m] = ||p1||^2 + ||p2||^2 - 2*p1.p2
// bf1 holds (-2*p1) in bf16, so MFMA acc = -2*cross directly.
// out = mean_n(min_m dist) + mean_m(min_n dist)

#define BATCH 8
#define NPTS 4096
#define DIM 128

using bf16x8 = __attribute__((ext_vector_type(8))) short;
using f32x4  = __attribute__((ext_vector_type(4))) float;

// ------------- K1: fp32 -> bf16 (p1 scaled by -2) + exact fp32 norms --------
__global__ void prep_kernel(const float* __restrict__ p1,
                            const float* __restrict__ p2,
                            __hip_bfloat16* __restrict__ b1,
                            __hip_bfloat16* __restrict__ b2,
                            float* __restrict__ s1,
                            float* __restrict__ s2) {
    const int arr = blockIdx.y;
    const float* src = arr ? p2 : p1;
    __hip_bfloat16* dst = arr ? b2 : b1;
    float* sq = arr ? s2 : s1;
    const float scale = arr ? 1.0f : -2.0f;

    const int wid = threadIdx.x >> 6;
    const int l   = threadIdx.x & 63;
    const int p   = blockIdx.x * 4 + wid;   // one wave per point
    const float2 v = *reinterpret_cast<const float2*>(src + (size_t)p * DIM + l * 2);
    float s = v.x * v.x + v.y * v.y;        // norm from ORIGINAL values
    __hip_bfloat162 h = __float22bfloat162_rn(make_float2(v.x * scale, v.y * scale));
    *reinterpret_cast<__hip_bfloat162*>(dst + (size_t)p * DIM + l * 2) = h;
    #pragma unroll
    for (int off = 1; off < 64; off <<= 1) s += __shfl_xor(s, off);
    if (l == 0) sq[p] = s;
}

// async global->LDS, 16B per lane; lds base must be wave-uniform.
__device__ __forceinline__ void stage16(const __hip_bfloat16* g, void* lds) {
    __builtin_amdgcn_global_load_lds(
        (const __attribute__((address_space(1))) void*)g,
        (__attribute__((address_space(3))) void*)lds, 16, 0, 0);
}

// ------------- K2: tiled GEMM + fused directional mins ----------------------
// grid (32 n-tiles, 4 m-quarters, 8 batches) = 1024 blocks, 256 threads.
// Block: 128 rows x 1024 cols (8 m-tiles of 128). Wave: 32 rows.
// B-tile double-buffered in LDS, staged via global_load_lds with the XOR
// swizzle applied to the SOURCE address (gload_lds writes linearly); the
// next tile's loads are issued before computing the current tile (2-phase
// pipeline, one barrier per tile).
// launch_bounds (256,2): forcing (256,4) made the allocator cut to 64 VGPR
// -> scratch spills (R2: FETCH 37->239MB, K2 63->128us). Do NOT force.
__global__ void __launch_bounds__(256, 2)
chamfer_tile_kernel(const __hip_bfloat16* __restrict__ bf1,
                    const __hip_bfloat16* __restrict__ bf2,
                    const float* __restrict__ sq1,
                    const float* __restrict__ sq2,
                    float* __restrict__ min1p,   // [B][4][NPTS]  (sq2 - 2c) row-mins
                    float* __restrict__ min2p) { // [B][128][NPTS] (sq1 - 2c) col-mins
    const int nt = blockIdx.x;
    const int mh = blockIdx.y;      // m quarter (1024 cols)
    const int b  = blockIdx.z;
    const int tid = threadIdx.x;
    const int wid = tid >> 6;
    const int l   = tid & 63;
    const int l15 = l & 15;
    const int lhi = l >> 4;

    __shared__ __align__(16) unsigned char btile[2][128 * 256]; // 2 x 32KB

    const __hip_bfloat16* bf1b = bf1 + (size_t)b * NPTS * DIM;
    const __hip_bfloat16* bf2b = bf2 + (size_t)b * NPTS * DIM;
    const float* sq2b = sq2 + b * NPTS;

    const int n0 = nt * 128 + wid * 32;  // wave's first row

    // A fragments: rows n0 + rt*16 + l15, k = ks*32 + lhi*8
    bf16x8 afrag[2][4];
    #pragma unroll
    for (int rt = 0; rt < 2; ++rt)
        #pragma unroll
        for (int ks = 0; ks < 4; ++ks)
            afrag[rt][ks] = *reinterpret_cast<const bf16x8*>(
                bf1b + (n0 + rt * 16 + l15) * DIM + ks * 32 + lhi * 8);

    // sq1 for accumulator rows: n0 + rt*16 + lhi*4 + j
    float sq1v[2][4];
    #pragma unroll
    for (int rt = 0; rt < 2; ++rt)
        #pragma unroll
        for (int j = 0; j < 4; ++j)
            sq1v[rt][j] = sq1[b * NPTS + n0 + rt * 16 + lhi * 4 + j];

    float rmin[2][4];
    #pragma unroll
    for (int rt = 0; rt < 2; ++rt)
        #pragma unroll
        for (int j = 0; j < 4; ++j) rmin[rt][j] = 3.4e38f;

    // wave-level stage of B tile at column m0 into buffer `buf`.
    // linear LDS slot (row,q) <- global column-block (q ^ (row&7)), so the
    // swizzled read  btile[row*256 + (kbyte ^ ((row&7)<<4))]  sees k=kbyte/2.
    auto STAGE = [&](int buf, int m0) {
        #pragma unroll
        for (int j = 0; j < 8; ++j) {
            const int c   = j * 256 + wid * 64 + l;   // [0, 2048)
            const int row = c >> 4;
            const int q   = c & 15;
            const __hip_bfloat16* src =
                bf2b + (size_t)(m0 + row) * DIM + (q ^ (row & 7)) * 8;
            stage16(src, &btile[buf][(j * 256 + wid * 64) * 16]);
        }
    };

    int cur = 0;
    STAGE(0, mh * 1024);
    __syncthreads();   // compiler drains vmcnt before the barrier

    for (int mt = 0; mt < 8; ++mt) {
        const int m0 = mh * 1024 + mt * 128;
        if (mt < 7) STAGE(cur ^ 1, m0 + 128);  // prefetch next tile

        // MFMA: acc = (-2*P1rows) x P2rows^T, K=128
        f32x4 acc[2][8];
        #pragma unroll
        for (int rt = 0; rt < 2; ++rt)
            #pragma unroll
            for (int ct = 0; ct < 8; ++ct) acc[rt][ct] = f32x4{0.f, 0.f, 0.f, 0.f};

        #pragma unroll
        for (int ks = 0; ks < 4; ++ks) {
            #pragma unroll
            for (int ct = 0; ct < 8; ++ct) {
                const int brow = ct * 16 + l15;
                const int kbyte = ks * 64 + lhi * 16;
                bf16x8 bfrag = *reinterpret_cast<const bf16x8*>(
                    &btile[cur][brow * 256 + (kbyte ^ ((brow & 7) << 4))]);
                #pragma unroll
                for (int rt = 0; rt < 2; ++rt)
                    acc[rt][ct] = __builtin_amdgcn_mfma_f32_16x16x32_bf16(
                        afrag[rt][ks], bfrag, acc[rt][ct], 0, 0, 0);
            }
        }

        // per-lane sq2 values for each col group (L1-resident, 512B/tile)
        float s2v[8];
        #pragma unroll
        for (int ct = 0; ct < 8; ++ct) s2v[ct] = sq2b[m0 + ct * 16 + l15];

        // dir1: row-mins (min over cols), min3-friendly pairs over ct
        #pragma unroll
        for (int rt = 0; rt < 2; ++rt)
            #pragma unroll
            for (int j = 0; j < 4; ++j) {
                float r = rmin[rt][j];
                #pragma unroll
                for (int cp = 0; cp < 4; ++cp) {
                    const float t0 = acc[rt][2 * cp][j]     + s2v[2 * cp];
                    const float t1 = acc[rt][2 * cp + 1][j] + s2v[2 * cp + 1];
                    r = fminf(r, fminf(t0, t1));   // v_min3
                }
                rmin[rt][j] = r;
            }

        // dir2: col-mins (min over this wave's 32 rows), pairs over j
        float cmin[8];
        #pragma unroll
        for (int ct = 0; ct < 8; ++ct) {
            float c = 3.4e38f;
            #pragma unroll
            for (int rt = 0; rt < 2; ++rt)
                #pragma unroll
                for (int jp = 0; jp < 2; ++jp) {
                    const float u0 = sq1v[rt][2 * jp]     + acc[rt][ct][2 * jp];
                    const float u1 = sq1v[rt][2 * jp + 1] + acc[rt][ct][2 * jp + 1];
                    c = fminf(c, fminf(u0, u1));   // v_min3
                }
            cmin[ct] = c;
        }

        // fold the 4 lhi row-groups, then write per-wave partial to global
        #pragma unroll
        for (int ct = 0; ct < 8; ++ct) {
            cmin[ct] = fminf(cmin[ct], __shfl_xor(cmin[ct], 16));
            cmin[ct] = fminf(cmin[ct], __shfl_xor(cmin[ct], 32));
        }
        if (l < 16) {
            float* dst = min2p + ((size_t)b * 128 + nt * 4 + wid) * NPTS + m0;
            #pragma unroll
            for (int ct = 0; ct < 8; ++ct) dst[ct * 16 + l] = cmin[ct];
        }

        __syncthreads();   // next-tile loads landed AND everyone done reading cur
        cur ^= 1;
    }

    // dir1 finalize: reduce across lane bits 0..3 (cols), write once per row
    #pragma unroll
    for (int rt = 0; rt < 2; ++rt)
        #pragma unroll
        for (int j = 0; j < 4; ++j) {
            float v = rmin[rt][j];
            v = fminf(v, __shfl_xor(v, 1));
            v = fminf(v, __shfl_xor(v, 2));
            v = fminf(v, __shfl_xor(v, 4));
            v = fminf(v, __shfl_xor(v, 8));
            rmin[rt][j] = v;
        }
    if (l15 == 0) {
        #pragma unroll
        for (int rt = 0; rt < 2; ++rt)
            #pragma unroll
            for (int j = 0; j < 4; ++j)
                min1p[((size_t)b * 4 + mh) * NPTS + n0 + rt * 16 + lhi * 4 + j] =
                    rmin[rt][j];
    }
}

// ------------- K3: combine partials, means, scalar out ----------------------
// 256 blocks x 256 threads = 65536 = 2 * B * NPTS (exact, no guards)
__global__ void finalize_kernel(const float* __restrict__ min1p,
                                const float* __restrict__ min2p,
                                const float* __restrict__ sq1,
                                const float* __restrict__ sq2,
                                float* __restrict__ out) {
    const int tid = threadIdx.x;
    const int gid = blockIdx.x * 256 + tid;
    float sum;

    if (gid < BATCH * NPTS) {
        // dir1: one (b,n) per thread
        const int b = gid >> 12, n = gid & (NPTS - 1);
        const float* p = min1p + (size_t)b * 4 * NPTS + n;
        float v = fminf(fminf(p[0], p[NPTS]), fminf(p[2 * NPTS], p[3 * NPTS]));
        sum = (v + sq1[gid]) * (1.0f / (BATCH * NPTS));
    } else {
        // dir2: one (b,m) per thread, reduce 128 partials (coalesced per j)
        const int idx = gid - BATCH * NPTS;
        const int b = idx >> 12, m = idx & (NPTS - 1);
        const float* p = min2p + (size_t)b * 128 * NPTS + m;
        float v0 = 3.4e38f, v1 = 3.4e38f;
        #pragma unroll 4
        for (int j = 0; j < 128; j += 2) {
            v0 = fminf(v0, p[(size_t)j * NPTS]);
            v1 = fminf(v1, p[(size_t)(j + 1) * NPTS]);
        }
        sum = (fminf(v0, v1) + sq2[idx]) * (1.0f / (BATCH * NPTS));
    }

    #pragma unroll
    for (int off = 1; off < 64; off <<= 1) sum += __shfl_xor(sum, off);
    __shared__ float wsum[4];
    if ((tid & 63) == 0) wsum[tid >> 6] = sum;
    __syncthreads();
    if (tid == 0) atomicAdd(out, wsum[0] + wsum[1] + wsum[2] + wsum[3]);
}

extern "C" void kernel_launch(void* const* d_in, const int* in_sizes, int n_in,
                              void* d_out, int out_size, void* d_ws, size_t ws_size,
                              hipStream_t stream) {
    const float* p1 = (const float*)d_in[0];
    const float* p2 = (const float*)d_in[1];
    float* out = (float*)d_out;

    const size_t npts_tot = (size_t)BATCH * NPTS;
    __hip_bfloat16* bf1 = (__hip_bfloat16*)d_ws;
    __hip_bfloat16* bf2 = bf1 + npts_tot * DIM;
    float* sq1   = (float*)(bf2 + npts_tot * DIM);
    float* sq2   = sq1 + npts_tot;
    float* min1p = sq2 + npts_tot;                         // [B][4][NPTS]
    float* min2p = min1p + (size_t)BATCH * 4 * NPTS;       // [B][128][NPTS]

    hipMemsetAsync(d_out, 0, sizeof(float), stream);

    prep_kernel<<<dim3(npts_tot / 4, 2), 256, 0, stream>>>(p1, p2, bf1, bf2, sq1, sq2);

    dim3 g2(32, 4, BATCH);
    chamfer_tile_kernel<<<g2, 256, 0, stream>>>(bf1, bf2, sq1, sq2, min1p, min2p);

    finalize_kernel<<<256, 256, 0, stream>>>(min1p, min2p, sq1, sq2, out);
}